// Round 15
// baseline (331.568 us; speedup 1.0000x reference)
//
#include <hip/hip_runtime.h>
#include <math.h>

#define EMB 1024
#define HEADS 16
#define HD 64
#define FF_DIM 4096
#define SEQ 2048
#define BATCH 2
#define NTOK (BATCH * SEQ)   // 4096

typedef __bf16 bf16x8 __attribute__((ext_vector_type(8)));
typedef float f32x4 __attribute__((ext_vector_type(4)));

__device__ __forceinline__ unsigned short f2bf(float f) {
    union { float f; unsigned int u; } v; v.f = f;
    unsigned int r = v.u + 0x7fff + ((v.u >> 16) & 1);  // RNE
    return (unsigned short)(r >> 16);
}

// gelu_tanh(x) = 0.5x(1+tanh(z)) = x*sigmoid(2z), z = c(x+0.044715x^3).
__device__ __forceinline__ float gelu_f(float x) {
    const float A = 1.5957691216057308f;   // 2c, c = sqrt(2/pi)
    const float B = 0.07135481282989427f;  // 2c*0.044715
    float zz = x * (A + B * x * x);
    return x * __builtin_amdgcn_rcpf(1.f + __expf(-zz));
}

#define GLOAD_LDS16(g, l)                                                      \
    __builtin_amdgcn_global_load_lds(                                          \
        (const __attribute__((address_space(1))) void*)(g),                    \
        (__attribute__((address_space(3))) void*)(l), 16, 0, 0)

// softmax scale folded into Q: 1/sqrt(64) * log2(e)
#define QSCALE 0.18033688011112730f

// ---------------------------------------------------------------------------
// LayerNorm: one block per row of 1024, fp32 in -> bf16 out
// ---------------------------------------------------------------------------
__global__ __launch_bounds__(256) void ln_kernel(const float* __restrict__ x,
                                                 const float* __restrict__ scale,
                                                 const float* __restrict__ shift,
                                                 unsigned short* __restrict__ out) {
    int row = blockIdx.x;
    const float* xr = x + (size_t)row * EMB;
    unsigned short* yr = out + (size_t)row * EMB;
    int t = threadIdx.x;

    float v[4];
    float s = 0.f, s2 = 0.f;
#pragma unroll
    for (int i = 0; i < 4; i++) {
        v[i] = xr[t + i * 256];
        s += v[i];
        s2 += v[i] * v[i];
    }
    for (int o = 32; o > 0; o >>= 1) {
        s += __shfl_down(s, o, 64);
        s2 += __shfl_down(s2, o, 64);
    }
    __shared__ float red[4], red2[4];
    int wave = t >> 6;
    if ((t & 63) == 0) { red[wave] = s; red2[wave] = s2; }
    __syncthreads();
    if (t == 0) {
        float a = 0.f, b = 0.f;
#pragma unroll
        for (int i = 0; i < 4; i++) { a += red[i]; b += red2[i]; }
        red[0] = a; red2[0] = b;
    }
    __syncthreads();
    float mean = red[0] * (1.f / EMB);
    float var = red2[0] * (1.f / EMB) - mean * mean;
    float rstd = rsqrtf(var + 1e-5f);
#pragma unroll
    for (int i = 0; i < 4; i++) {
        int c = t + i * 256;
        yr[c] = f2bf(scale[c] * (v[i] - mean) * rstd + shift[c]);
    }
}

// ---------------------------------------------------------------------------
// Fused prep: blocks [0,3072) = weight transpose+cast (6 weights),
//             blocks [3072,7168) = LN1 row (x -> lnO bf16).
// ---------------------------------------------------------------------------
__global__ __launch_bounds__(256) void prep_kernel(
    const float* __restrict__ w0, const float* __restrict__ w1,
    const float* __restrict__ w2, const float* __restrict__ w3,
    const float* __restrict__ w4, const float* __restrict__ w5,
    unsigned short* __restrict__ o0, unsigned short* __restrict__ o1,
    unsigned short* __restrict__ o2, unsigned short* __restrict__ o3,
    unsigned short* __restrict__ o4, unsigned short* __restrict__ o5,
    const float* __restrict__ x, const float* __restrict__ ln1s,
    const float* __restrict__ ln1b, unsigned short* __restrict__ lnO) {
    __shared__ float tile[64][65];
    __shared__ float red[4], red2[4];
    int id = blockIdx.x;
    int t = threadIdx.x;

    if (id >= 3072) {
        int row = id - 3072;
        const float* xr = x + (size_t)row * EMB;
        unsigned short* yr = lnO + (size_t)row * EMB;
        float v[4];
        float s = 0.f, s2 = 0.f;
#pragma unroll
        for (int i = 0; i < 4; i++) {
            v[i] = xr[t + i * 256];
            s += v[i];
            s2 += v[i] * v[i];
        }
        for (int o = 32; o > 0; o >>= 1) {
            s += __shfl_down(s, o, 64);
            s2 += __shfl_down(s2, o, 64);
        }
        int wave = t >> 6;
        if ((t & 63) == 0) { red[wave] = s; red2[wave] = s2; }
        __syncthreads();
        if (t == 0) {
            float a = 0.f, b = 0.f;
#pragma unroll
            for (int i = 0; i < 4; i++) { a += red[i]; b += red2[i]; }
            red[0] = a; red2[0] = b;
        }
        __syncthreads();
        float mean = red[0] * (1.f / EMB);
        float var = red2[0] * (1.f / EMB) - mean * mean;
        float rstd = rsqrtf(var + 1e-5f);
#pragma unroll
        for (int i = 0; i < 4; i++) {
            int c = t + i * 256;
            yr[c] = f2bf(ln1s[c] * (v[i] - mean) * rstd + ln1b[c]);
        }
        return;
    }

    const float* src; unsigned short* dst; int K, N, lid;
    if (id < 256)       { src = w0; dst = o0; K = 1024; N = 1024; lid = id; }
    else if (id < 512)  { src = w1; dst = o1; K = 1024; N = 1024; lid = id - 256; }
    else if (id < 768)  { src = w2; dst = o2; K = 1024; N = 1024; lid = id - 512; }
    else if (id < 1024) { src = w3; dst = o3; K = 1024; N = 1024; lid = id - 768; }
    else if (id < 2048) { src = w4; dst = o4; K = 1024; N = 4096; lid = id - 1024; }
    else                { src = w5; dst = o5; K = 4096; N = 1024; lid = id - 2048; }
    int tn = N >> 6;
    int k0 = (lid / tn) << 6, n0 = (lid % tn) << 6;
    int rr = t >> 6, cc = t & 63;
#pragma unroll
    for (int i = 0; i < 16; i++) {
        int r = i * 4 + rr;
        tile[r][cc] = src[(size_t)(k0 + r) * N + n0 + cc];
    }
    __syncthreads();
#pragma unroll
    for (int i = 0; i < 16; i++) {
        int r = i * 4 + rr;
        dst[(size_t)(n0 + r) * K + k0 + cc] = f2bf(tile[cc][r]);
    }
}

// ===========================================================================
// BK=64 staging geometry: LDS row = 64 elems (128 B) = 8 x 16B chunks.
// Physical chunk p of row r holds logical chunk p ^ (r & 7); fragment
// ds_read_b128 aliases 2-way (free).
// ===========================================================================

// ---------------------------------------------------------------------------
// FF1 GEMM, 128x64 tile, BK=64 double-buffered. LDS 48 KB -> 3 resident/CU
// (was 128x128 @ 64 KB -> only 2). Grid 2048 (1D): m = bid&31, n = bid>>5;
// XCD = bid%8 = m%8 -> A (ln2 out) locality preserved.
// Wave w: rows [w*32,+32) x all 64 cols: 2x4 frags, per s 6 reads / 8 MFMA.
// Epilogue: bf16 gelu(acc + bias[n]).
// ---------------------------------------------------------------------------
__global__ __launch_bounds__(256) void ff1_gemm(
    const unsigned short* __restrict__ A,   // M x K bf16
    const unsigned short* __restrict__ Bt,  // N x K bf16
    unsigned short* __restrict__ C,
    const float* __restrict__ bias,
    int M, int N, int K) {
    __shared__ unsigned short As[2][128 * 64];  // 32 KB
    __shared__ unsigned short Bs[2][64 * 64];   // 16 KB

    const int t = threadIdx.x;
    const int w = t >> 6, lane = t & 63;
    const int bid = blockIdx.x;
    const int m0 = (bid & 31) * 128, n0 = (bid >> 5) * 64;

    const int srow = lane >> 3;
    const int sc = (lane & 7) ^ srow;
    const unsigned short* gA[4];
#pragma unroll
    for (int i = 0; i < 4; i++)
        gA[i] = A + (size_t)(m0 + i * 32 + w * 8 + srow) * K + sc * 8;
    const unsigned short* gB[2];
#pragma unroll
    for (int i = 0; i < 2; i++)
        gB[i] = Bt + (size_t)(n0 + i * 32 + w * 8 + srow) * K + sc * 8;

    int ph[2];
#pragma unroll
    for (int s = 0; s < 2; s++) ph[s] = ((s * 4 + (lane >> 4)) ^ (lane & 7)) * 8;
    int abase[2], bbase[4];
#pragma unroll
    for (int i = 0; i < 2; i++) abase[i] = (w * 32 + i * 16 + (lane & 15)) * 64;
#pragma unroll
    for (int j = 0; j < 4; j++) bbase[j] = (j * 16 + (lane & 15)) * 64;

    f32x4 acc[2][4];
#pragma unroll
    for (int i = 0; i < 2; i++)
#pragma unroll
        for (int j = 0; j < 4; j++) acc[i][j] = (f32x4){0.f, 0.f, 0.f, 0.f};

#define STGF(b)                                                                \
    do {                                                                       \
        _Pragma("unroll") for (int i_ = 0; i_ < 4; i_++) {                     \
            GLOAD_LDS16(gA[i_], &As[b][(i_ * 32 + w * 8) * 64]);               \
            gA[i_] += 64;                                                      \
        }                                                                      \
        _Pragma("unroll") for (int i_ = 0; i_ < 2; i_++) {                     \
            GLOAD_LDS16(gB[i_], &Bs[b][(i_ * 32 + w * 8) * 64]);               \
            gB[i_] += 64;                                                      \
        }                                                                      \
    } while (0)

    STGF(0);
    const int nk = K >> 6;
    for (int it = 0; it < nk; it++) {
        const int buf = it & 1;
        __syncthreads();
        if (it + 1 < nk) STGF(buf ^ 1);
#pragma unroll
        for (int s = 0; s < 2; s++) {
            bf16x8 af[2], bfr[4];
#pragma unroll
            for (int i = 0; i < 2; i++)
                af[i] = *reinterpret_cast<const bf16x8*>(&As[buf][abase[i] + ph[s]]);
#pragma unroll
            for (int j = 0; j < 4; j++)
                bfr[j] = *reinterpret_cast<const bf16x8*>(&Bs[buf][bbase[j] + ph[s]]);
#pragma unroll
            for (int i = 0; i < 2; i++)
#pragma unroll
                for (int j = 0; j < 4; j++)
                    acc[i][j] = __builtin_amdgcn_mfma_f32_16x16x32_bf16(
                        af[i], bfr[j], acc[i][j], 0, 0, 0);
        }
    }
#undef STGF

    const int ccol = lane & 15;
    const int crow = (lane >> 4) << 2;
#pragma unroll
    for (int i = 0; i < 2; i++) {
#pragma unroll
        for (int j = 0; j < 4; j++) {
            int col = n0 + j * 16 + ccol;
            float badd = bias[col];
#pragma unroll
            for (int r = 0; r < 4; r++) {
                int row = m0 + w * 32 + i * 16 + crow + r;
                C[(size_t)row * N + col] = f2bf(gelu_f(acc[i][j][r] + badd));
            }
        }
    }
}

// ---------------------------------------------------------------------------
// N=1024 GEMM, 64x64 tile, BK=64 double-buffered (O-proj / FF2).
// Grid (M/64, N/64) = 64x16 = 1024 blocks = 4/CU; XCD = x%8 (m-locality).
// EPI 1: C = acc + bias[n] + resid (fp32)       [O-proj]
// EPI 3: C += acc + bias[n]        (fp32 RMW)   [FF2]
// ---------------------------------------------------------------------------
template <int EPI>
__global__ __launch_bounds__(256) void mfma_gemm_s64(
    const unsigned short* __restrict__ A,   // M x K bf16
    const unsigned short* __restrict__ Bt,  // N x K bf16
    float* __restrict__ C,
    const float* __restrict__ bias,
    const float* __restrict__ resid,
    int M, int N, int K) {
    __shared__ unsigned short As[2][64 * 64];  // 16 KB
    __shared__ unsigned short Bs[2][64 * 64];  // 16 KB

    const int t = threadIdx.x;
    const int w = t >> 6, lane = t & 63;
    const int m0 = blockIdx.x * 64, n0 = blockIdx.y * 64;

    const int srow = lane >> 3;
    const int sc = (lane & 7) ^ srow;
    const unsigned short* gA[2];
    const unsigned short* gB[2];
#pragma unroll
    for (int i = 0; i < 2; i++) {
        gA[i] = A + (size_t)(m0 + i * 32 + w * 8 + srow) * K + sc * 8;
        gB[i] = Bt + (size_t)(n0 + i * 32 + w * 8 + srow) * K + sc * 8;
    }

    int ph[2];
#pragma unroll
    for (int s = 0; s < 2; s++) ph[s] = ((s * 4 + (lane >> 4)) ^ (lane & 7)) * 8;
    const int mrow = (w >> 1) * 32, ncol = (w & 1) * 32;
    int abase[2], bbase[2];
#pragma unroll
    for (int i = 0; i < 2; i++) {
        abase[i] = (mrow + i * 16 + (lane & 15)) * 64;
        bbase[i] = (ncol + i * 16 + (lane & 15)) * 64;
    }

    f32x4 acc[2][2];
#pragma unroll
    for (int i = 0; i < 2; i++)
#pragma unroll
        for (int j = 0; j < 2; j++) acc[i][j] = (f32x4){0.f, 0.f, 0.f, 0.f};

#define STGS(b)                                                                \
    do {                                                                       \
        _Pragma("unroll") for (int i_ = 0; i_ < 2; i_++) {                     \
            GLOAD_LDS16(gA[i_], &As[b][(i_ * 32 + w * 8) * 64]);               \
            GLOAD_LDS16(gB[i_], &Bs[b][(i_ * 32 + w * 8) * 64]);               \
            gA[i_] += 64; gB[i_] += 64;                                        \
        }                                                                      \
    } while (0)

    STGS(0);
    const int nk = K >> 6;
    for (int it = 0; it < nk; it++) {
        const int buf = it & 1;
        __syncthreads();
        if (it + 1 < nk) STGS(buf ^ 1);
#pragma unroll
        for (int s = 0; s < 2; s++) {
            bf16x8 af[2], bfr[2];
#pragma unroll
            for (int i = 0; i < 2; i++) {
                af[i] = *reinterpret_cast<const bf16x8*>(&As[buf][abase[i] + ph[s]]);
                bfr[i] = *reinterpret_cast<const bf16x8*>(&Bs[buf][bbase[i] + ph[s]]);
            }
#pragma unroll
            for (int i = 0; i < 2; i++)
#pragma unroll
                for (int j = 0; j < 2; j++)
                    acc[i][j] = __builtin_amdgcn_mfma_f32_16x16x32_bf16(
                        af[i], bfr[j], acc[i][j], 0, 0, 0);
        }
    }
#undef STGS

    const int ccol = lane & 15;
    const int crow = (lane >> 4) << 2;
#pragma unroll
    for (int i = 0; i < 2; i++) {
#pragma unroll
        for (int j = 0; j < 2; j++) {
            int col = n0 + ncol + j * 16 + ccol;
            float badd = bias[col];
#pragma unroll
            for (int r = 0; r < 4; r++) {
                int row = m0 + mrow + i * 16 + crow + r;
                size_t idx = (size_t)row * N + col;
                if constexpr (EPI == 1) {
                    C[idx] = acc[i][j][r] + badd + resid[idx];
                } else {
                    C[idx] = C[idx] + acc[i][j][r] + badd;
                }
            }
        }
    }
}

// ---------------------------------------------------------------------------
// Fused QKV, 128x64 tiles, BK=64 double-buffered (48 KB -> 3 resident/CU).
// Grid 1536 (1D):
//   [0,1024):  qk: m = bid&31 (XCD = m%8), n = bid>>5 over 2048 cols
//              -> q (scaled by QSCALE) or kb, bf16 [tok][1024]
//   [1024,1536): v: A=wvT m = lb&7, n = lb>>3 over 4096 -> vT[1024][4096]
// ---------------------------------------------------------------------------
__global__ __launch_bounds__(256) void qkv_gemm(
    const unsigned short* __restrict__ lnO,   // [4096][1024]
    const unsigned short* __restrict__ wqkT,  // [2048][1024]
    const unsigned short* __restrict__ wvT,   // [1024][1024]
    unsigned short* __restrict__ q,           // [4096][1024]
    unsigned short* __restrict__ kb,          // [4096][1024]
    unsigned short* __restrict__ vT) {        // [1024][4096]
    __shared__ unsigned short As[2][128 * 64];  // 32 KB
    __shared__ unsigned short Bs[2][64 * 64];   // 16 KB

    const int t = threadIdx.x;
    const int w = t >> 6, lane = t & 63;
    const int bid = blockIdx.x;
    const bool qk = bid < 1024;

    const unsigned short *A, *Bt;
    int m0, n0;
    if (qk) {
        A = lnO; Bt = wqkT;
        m0 = (bid & 31) * 128; n0 = (bid >> 5) * 64;
    } else {
        int lb = bid - 1024;
        A = wvT; Bt = lnO;
        m0 = (lb & 7) * 128; n0 = (lb >> 3) * 64;
    }
    const int K = 1024;

    const int srow = lane >> 3;
    const int sc = (lane & 7) ^ srow;
    const unsigned short* gA[4];
#pragma unroll
    for (int i = 0; i < 4; i++)
        gA[i] = A + (size_t)(m0 + i * 32 + w * 8 + srow) * K + sc * 8;
    const unsigned short* gB[2];
#pragma unroll
    for (int i = 0; i < 2; i++)
        gB[i] = Bt + (size_t)(n0 + i * 32 + w * 8 + srow) * K + sc * 8;

    int ph[2];
#pragma unroll
    for (int s = 0; s < 2; s++) ph[s] = ((s * 4 + (lane >> 4)) ^ (lane & 7)) * 8;
    int abase[2], bbase[4];
#pragma unroll
    for (int i = 0; i < 2; i++) abase[i] = (w * 32 + i * 16 + (lane & 15)) * 64;
#pragma unroll
    for (int j = 0; j < 4; j++) bbase[j] = (j * 16 + (lane & 15)) * 64;

    f32x4 acc[2][4];
#pragma unroll
    for (int i = 0; i < 2; i++)
#pragma unroll
        for (int j = 0; j < 4; j++) acc[i][j] = (f32x4){0.f, 0.f, 0.f, 0.f};

#define STGQ(b)                                                                \
    do {                                                                       \
        _Pragma("unroll") for (int i_ = 0; i_ < 4; i_++) {                     \
            GLOAD_LDS16(gA[i_], &As[b][(i_ * 32 + w * 8) * 64]);               \
            gA[i_] += 64;                                                      \
        }                                                                      \
        _Pragma("unroll") for (int i_ = 0; i_ < 2; i_++) {                     \
            GLOAD_LDS16(gB[i_], &Bs[b][(i_ * 32 + w * 8) * 64]);               \
            gB[i_] += 64;                                                      \
        }                                                                      \
    } while (0)

    STGQ(0);
    const int nk = K >> 6;
    for (int it = 0; it < nk; it++) {
        const int buf = it & 1;
        __syncthreads();
        if (it + 1 < nk) STGQ(buf ^ 1);
#pragma unroll
        for (int s = 0; s < 2; s++) {
            bf16x8 af[2], bfr[4];
#pragma unroll
            for (int i = 0; i < 2; i++)
                af[i] = *reinterpret_cast<const bf16x8*>(&As[buf][abase[i] + ph[s]]);
#pragma unroll
            for (int j = 0; j < 4; j++)
                bfr[j] = *reinterpret_cast<const bf16x8*>(&Bs[buf][bbase[j] + ph[s]]);
#pragma unroll
            for (int i = 0; i < 2; i++)
#pragma unroll
                for (int j = 0; j < 4; j++)
                    acc[i][j] = __builtin_amdgcn_mfma_f32_16x16x32_bf16(
                        af[i], bfr[j], acc[i][j], 0, 0, 0);
        }
    }
#undef STGQ

    const int ccol = lane & 15;
    const int crow = (lane >> 4) << 2;
    unsigned short* dst;
    int nbase, ldc;
    float scale = 1.f;
    if (qk) {
        if (n0 < 1024) { dst = q; scale = QSCALE; }  // fold softmax scale into Q
        else dst = kb;
        nbase = n0 & 1023;
        ldc = 1024;
    } else {
        dst = vT;
        nbase = n0;
        ldc = 4096;
    }
#pragma unroll
    for (int i = 0; i < 2; i++) {
#pragma unroll
        for (int j = 0; j < 4; j++) {
            int col = nbase + j * 16 + ccol;
#pragma unroll
            for (int r = 0; r < 4; r++) {
                int row = m0 + w * 32 + i * 16 + crow + r;
                dst[(size_t)row * ldc + col] = f2bf(acc[i][j][r] * scale);
            }
        }
    }
}

// ---------------------------------------------------------------------------
// MFMA causal flash attention v6: balanced pairing + XCD-local K/V +
// Q pre-scaled by 0.125*log2e -> P = exp2(S) directly (no fma, no fixed-max
// subtract; the constant factor cancels in the l-normalization).
// ---------------------------------------------------------------------------
__global__ __launch_bounds__(256) void attn_mfma(
    const unsigned short* __restrict__ Q,   // [4096][1024], pre-scaled
    const unsigned short* __restrict__ K,   // [4096][1024]
    const unsigned short* __restrict__ Vt,  // [1024][4096]
    unsigned short* __restrict__ O) {       // [4096][1024]
    __shared__ unsigned short Ks[2][64 * 64];
    __shared__ unsigned short Vs[2][64 * 64];
    __shared__ unsigned short Ps[4][16 * 64];

    const int t = threadIdx.x;
    const int w = t >> 6, lane = t & 63;
    const int l15 = lane & 15, l4 = lane >> 4;
    const int bh = blockIdx.x;    // 0..31  (same-bh -> same XCD)
    const int b = bh >> 4, h = bh & 15;
    const int pair = blockIdx.y;  // 0..15

    const int sr = (w << 3) + (lane >> 3);   // 0..31
    const int sc = lane & 7;
    const int c = sc ^ (sr & 7);
    const unsigned short* kbase = K + ((size_t)(b * SEQ)) * EMB + h * HD;
    const unsigned short* vbase = Vt + ((size_t)(h * HD)) * (size_t)NTOK + (size_t)b * SEQ;
    unsigned short* Pw = &Ps[w][0];

#define STAGE(k0s, buf)                                                        \
    do {                                                                       \
        GLOAD_LDS16(kbase + (size_t)((k0s) + sr) * EMB + c * 8,                \
                    &Ks[buf][(w << 3) * 64]);                                  \
        GLOAD_LDS16(kbase + (size_t)((k0s) + sr + 32) * EMB + c * 8,           \
                    &Ks[buf][((w << 3) + 32) * 64]);                           \
        GLOAD_LDS16(vbase + (size_t)sr * NTOK + (k0s) + c * 8,                 \
                    &Vs[buf][(w << 3) * 64]);                                  \
        GLOAD_LDS16(vbase + (size_t)(sr + 32) * NTOK + (k0s) + c * 8,          \
                    &Vs[buf][((w << 3) + 32) * 64]);                           \
    } while (0)

#pragma unroll
    for (int phase = 0; phase < 2; phase++) {
        const int qt = phase ? pair : (31 - pair);
        const int q0 = qt * 64;

        const unsigned short* qg =
            Q + ((size_t)(b * SEQ + q0 + w * 16 + l15)) * EMB + h * HD + l4 * 8;
        bf16x8 qf0 = *(const bf16x8*)qg;
        bf16x8 qf1 = *(const bf16x8*)(qg + 32);
        const int qrow_c = q0 + w * 16 + l4 * 4;

        float lsum[4] = {0.f, 0.f, 0.f, 0.f};
        f32x4 Oacc[4];
#pragma unroll
        for (int j = 0; j < 4; j++) Oacc[j] = (f32x4){0.f, 0.f, 0.f, 0.f};

        const int ntiles = qt + 1;
        __syncthreads();
        STAGE(0, 0);
        for (int tile = 0; tile < ntiles; tile++) {
            const int k0 = tile * 64;
            const int buf = tile & 1;
            __syncthreads();
            if (tile + 1 < ntiles) STAGE(k0 + 64, buf ^ 1);

            f32x4 S[4];
#pragma unroll
            for (int j = 0; j < 4; j++) S[j] = (f32x4){0.f, 0.f, 0.f, 0.f};
#pragma unroll
            for (int s = 0; s < 2; s++) {
                bf16x8 qf = s ? qf1 : qf0;
#pragma unroll
                for (int j = 0; j < 4; j++) {
                    int rk = 16 * j + l15;
                    int phys = (s * 4 + l4) ^ (rk & 7);
                    bf16x8 kf = *(const bf16x8*)&Ks[buf][rk * 64 + phys * 8];
                    S[j] = __builtin_amdgcn_mfma_f32_16x16x32_bf16(qf, kf, S[j], 0, 0, 0);
                }
            }

            // P = exp2(S) — Q carries the softmax scale; constant factor
            // cancels in l-normalization. Mask only the diag tile.
            if (tile == ntiles - 1) {
#pragma unroll
                for (int j = 0; j < 4; j++)
#pragma unroll
                    for (int r = 0; r < 4; r++) {
                        float e = exp2f(S[j][r]);
                        if (k0 + 16 * j + l15 > qrow_c + r) e = 0.f;
                        S[j][r] = e;
                        lsum[r] += e;
                    }
            } else {
#pragma unroll
                for (int j = 0; j < 4; j++)
#pragma unroll
                    for (int r = 0; r < 4; r++) {
                        float e = exp2f(S[j][r]);
                        S[j][r] = e;
                        lsum[r] += e;
                    }
            }

#pragma unroll
            for (int r = 0; r < 4; r++) {
                int row = l4 * 4 + r;
#pragma unroll
                for (int j = 0; j < 4; j++) {
                    int col = 16 * j + l15;
                    int phys = (col >> 3) ^ (row & 7);
                    Pw[row * 64 + phys * 8 + (col & 7)] = f2bf(S[j][r]);
                }
            }

#pragma unroll
            for (int s = 0; s < 2; s++) {
                int pphys = (s * 4 + l4) ^ (l15 & 7);
                bf16x8 pf = *(const bf16x8*)&Pw[l15 * 64 + pphys * 8];
#pragma unroll
                for (int j = 0; j < 4; j++) {
                    int rv = 16 * j + l15;
                    int vphys = (s * 4 + l4) ^ (rv & 7);
                    bf16x8 vf = *(const bf16x8*)&Vs[buf][rv * 64 + vphys * 8];
                    Oacc[j] = __builtin_amdgcn_mfma_f32_16x16x32_bf16(pf, vf, Oacc[j], 0, 0, 0);
                }
            }
        }

#pragma unroll
        for (int r = 0; r < 4; r++) {
            float l = lsum[r];
#pragma unroll
            for (int off = 1; off < 16; off <<= 1)
                l += __shfl_xor(l, off, 64);
            float inv = 1.f / l;
            size_t rowb = (size_t)(b * SEQ + qrow_c + r) * EMB + h * HD;
#pragma unroll
            for (int j = 0; j < 4; j++)
                O[rowb + 16 * j + l15] = f2bf(Oacc[j][r] * inv);
        }
    }
#undef STAGE
}

// ---------------------------------------------------------------------------
// launch
// ---------------------------------------------------------------------------
extern "C" void kernel_launch(void* const* d_in, const int* in_sizes, int n_in,
                              void* d_out, int out_size, void* d_ws, size_t ws_size,
                              hipStream_t stream) {
    const float* x     = (const float*)d_in[0];
    const float* w_q   = (const float*)d_in[1];
    const float* w_k   = (const float*)d_in[2];
    const float* w_v   = (const float*)d_in[3];
    const float* w_o   = (const float*)d_in[4];
    const float* b_o   = (const float*)d_in[5];
    const float* ln1s  = (const float*)d_in[6];
    const float* ln1b  = (const float*)d_in[7];
    const float* ln2s  = (const float*)d_in[8];
    const float* ln2b  = (const float*)d_in[9];
    const float* w_ff1 = (const float*)d_in[10];
    const float* b_ff1 = (const float*)d_in[11];
    const float* w_ff2 = (const float*)d_in[12];
    const float* b_ff2 = (const float*)d_in[13];
    float* out = (float*)d_out;

    char* p = (char*)d_ws;
    unsigned short* lnO  = (unsigned short*)p; p += (size_t)NTOK * EMB * 2;      // 8 MB
    unsigned short* q    = (unsigned short*)p; p += (size_t)NTOK * EMB * 2;
    unsigned short* kbuf = (unsigned short*)p; p += (size_t)NTOK * EMB * 2;
    unsigned short* vT   = (unsigned short*)p; p += (size_t)NTOK * EMB * 2;
    unsigned short* ctx  = (unsigned short*)p; p += (size_t)NTOK * EMB * 2;      // attn out, later LN2 out
    unsigned short* ff1a = (unsigned short*)p; p += (size_t)NTOK * FF_DIM * 2;   // 32 MB
    unsigned short* wqkT = (unsigned short*)p; p += (size_t)2 * EMB * EMB * 2;   // 4 MB
    unsigned short* wvT  = (unsigned short*)p; p += (size_t)EMB * EMB * 2;
    unsigned short* woT  = (unsigned short*)p; p += (size_t)EMB * EMB * 2;
    unsigned short* wf1T = (unsigned short*)p; p += (size_t)FF_DIM * EMB * 2;    // 8 MB
    unsigned short* wf2T = (unsigned short*)p; p += (size_t)EMB * FF_DIM * 2;    // 8 MB

    dim3 blk(256);
    dim3 gS64(NTOK / 64, EMB / 64);         // 64 m x 16 n = 1024 blocks = 4/CU
    dim3 gAttn(BATCH * HEADS, 16);          // bh x pair; same-bh -> same XCD

    // fused weight transpose+cast + LN1
    prep_kernel<<<3072 + NTOK, blk, 0, stream>>>(
        w_q, w_k, w_v, w_o, w_ff1, w_ff2,
        wqkT, wqkT + (size_t)EMB * EMB, wvT, woT, wf1T, wf2T,
        x, ln1s, ln1b, lnO);
    // QKV: 128x64 tiles, 1536 blocks = 3 resident/CU
    qkv_gemm<<<1536, blk, 0, stream>>>(lnO, wqkT, wvT, q, kbuf, vT);
    attn_mfma<<<gAttn, blk, 0, stream>>>(q, kbuf, vT, ctx);
    // O-proj fused: out = x + b_o + ctx @ w_o
    mfma_gemm_s64<1><<<gS64, blk, 0, stream>>>(ctx, woT, out, b_o, x, NTOK, EMB, EMB);
    // LN2: out -> ctx (bf16)
    ln_kernel<<<NTOK, blk, 0, stream>>>(out, ln2s, ln2b, ctx);
    // FF1: 128x64 tiles, 2048 blocks = 3 resident/CU, cheap gelu epilogue
    ff1_gemm<<<2048, blk, 0, stream>>>(ctx, wf1T, ff1a, b_ff1, NTOK, FF_DIM, EMB);
    // FF2 fused RMW: out += ff1a @ w_ff2 + b_ff2
    mfma_gemm_s64<3><<<gS64, blk, 0, stream>>>(ff1a, wf2T, out, b_ff2, nullptr, NTOK, EMB, FF_DIM);
}